// Round 4
// baseline (1223.570 us; speedup 1.0000x reference)
//
#include <hip/hip_runtime.h>
#include <math.h>

#define HDIM 1024
#define NWG 128
#define TPB 512
#define CONV_TOL 1.0e-5f

typedef unsigned long long u64;
typedef unsigned int u32;

struct RecArgs {
  const float* whh_l; const float* whh_r;
  const float* glc; const float* glf; const float* grc; const float* grf;
  u64* hq;            // [2][HDIM] tagged slots: low32 = tag | stable<<31, high32 = f32 bits
  float* hsl;         // [n][HDIM]
  float* hsr;         // [n][HDIM]
  const int* pstart; const int* pend;
  int n;
};

// ---------------- setup: target vector, special rows, tagged-state init, accum zeroing ----------------
__global__ void setup_kernel(const int* __restrict__ x, const int* ts, const int* te,
                             const float* __restrict__ emb,
                             float* target, float* seqfl, float* seqfr,
                             u64* hq, float* beta, float* svec, int n) {
  int e = threadIdx.x;  // 0..1023
  int start = ts[0], end = te[0];
  int first_l = (start > 0) ? 0 : (end + 1);
  int first_r = (end < n - 1) ? (n - 1) : (start - 1);
  int fl = min(max(first_l, 0), n - 1);
  int fr = min(max(first_r, 0), n - 1);
  float sum = 0.f;
  for (int p = start; p <= end; ++p) sum += emb[(size_t)x[p] * HDIM + e];
  target[e] = sum / (float)(end - start + 1);
  seqfl[e] = emb[(size_t)x[fl] * HDIM + e];
  seqfr[e] = emb[(size_t)x[fr] * HDIM + e];
  // tag=0 (h input for step 0), value = 0.0f, stable=0 — both parities
  hq[e] = 0ull;
  hq[HDIM + e] = 0ull;
  for (int i = e; i < n; i += 1024) beta[i] = 0.f;
  svec[e] = 0.f;
}

// ---------------- gate-constant vectors: w_ih@v + b_ih + b_hh ----------------
__global__ __launch_bounds__(256) void gateconst_kernel(
    const float* __restrict__ wih_l, const float* bih_l, const float* bhh_l,
    const float* __restrict__ wih_r, const float* bih_r, const float* bhh_r,
    const float* __restrict__ target, const float* __restrict__ seqfl,
    const float* __restrict__ seqfr,
    float* glc, float* glf, float* grc, float* grf) {
  int side = blockIdx.y;
  const float* wih = side ? wih_r : wih_l;
  const float* bih = side ? bih_r : bih_l;
  const float* bhh = side ? bhh_r : bhh_l;
  const float* sf = side ? seqfr : seqfl;
  float* outc = side ? grc : glc;
  float* outf = side ? grf : glf;
  int wv = threadIdx.x >> 6, lane = threadIdx.x & 63;
  int r = blockIdx.x * 4 + wv;  // 0..4095
  const float4* wrow = (const float4*)(wih + (size_t)r * HDIM);
  const float4* tg4 = (const float4*)target;
  const float4* sf4 = (const float4*)sf;
  float dc = 0.f, df = 0.f;
#pragma unroll
  for (int k = 0; k < 4; ++k) {
    float4 w4 = wrow[lane + 64 * k];
    float4 t4 = tg4[lane + 64 * k];
    float4 s4 = sf4[lane + 64 * k];
    dc += w4.x * t4.x + w4.y * t4.y + w4.z * t4.z + w4.w * t4.w;
    df += w4.x * s4.x + w4.y * s4.y + w4.z * s4.z + w4.w * s4.w;
  }
  for (int off = 32; off; off >>= 1) {
    dc += __shfl_xor(dc, off);
    df += __shfl_xor(df, off);
  }
  if (lane == 0) {
    float bb = bih[r] + bhh[r];
    outc[r] = dc + bb;
    outf[r] = df + bb;
  }
}

// ---------------- persistent recurrence (plain launch; shuffle-tree reduce; per-wave gates) ----------------
// 512 threads: waves 0..7, wave v owns h-unit w*8+v. Threads 0..255 poll (layout identical
// to previous version). Matvec: thread (chunk=tid&31, rowgrp=tid>>5) handles local rows
// 2*rowgrp, 2*rowgrp+1; row partials for the 32 chunks live in one half-wave -> shfl_xor tree.
__global__ __launch_bounds__(TPB, 1) void rec_kernel(RecArgs a) {
  const int w = blockIdx.x;
  const int tid = threadIdx.x;
  const int wave = tid >> 6;     // 0..7 == owned unit index
  const int lane = tid & 63;
  const int chunk = tid & 31;    // 32-col chunk of the k dimension
  const int rowgrp = tid >> 5;   // 0..15 -> local rows rowgrp*2, rowgrp*2+1
  const int n = a.n;

  __shared__ float lds_h[HDIM];
  __shared__ float lds_row[32];   // per-step row sums (4 gates x 8 units)
  __shared__ float lds_h8[2][8];  // [parity][unit]
  __shared__ int lds_conv[4];

  const int start = a.pstart[0];
  const int end = a.pend[0];
  const int first_l = (start > 0) ? 0 : (end + 1);
  const int first_r = (end < n - 1) ? (n - 1) : (start - 1);

  float4 wreg[2][8];  // constant-indexed only => guaranteed VGPR residency
  float cstate = 0.f;
  float hp0 = 0.f, hp1 = 0.f, cp0 = 0.f, cp1 = 0.f;  // parity history (wave-lane0 only)

  for (int pass = 0; pass < 2; ++pass) {
    const float* whh = pass ? a.whh_r : a.whh_l;
    const float* gcv = pass ? a.grc : a.glc;
    const float* gfv = pass ? a.grf : a.glf;
    float* hsout = pass ? a.hsr : a.hsl;
    const int tspecial = pass ? (n - 1 - first_r) : first_l;
    const int sbase = pass * n;

#pragma unroll
    for (int r = 0; r < 2; ++r) {
      const int lr = rowgrp * 2 + r;
      const int grow = (lr >> 3) * HDIM + w * 8 + (lr & 7);
      const float4* wr = (const float4*)(whh + (size_t)grow * HDIM) + chunk * 8;
#pragma unroll
      for (int i = 0; i < 8; ++i) wreg[r][i] = wr[(i + chunk) & 7];
    }
    // gate constants for this wave's unit (lane 0 only uses them)
    float gc0 = 0.f, gc1 = 0.f, gc2 = 0.f, gc3 = 0.f;
    float gf0 = 0.f, gf1 = 0.f, gf2c = 0.f, gf3 = 0.f;
    if (lane == 0) {
      const int base = w * 8 + wave;
      gc0 = gcv[base];            gc1 = gcv[HDIM + base];
      gc2 = gcv[2 * HDIM + base]; gc3 = gcv[3 * HDIM + base];
      gf0 = gfv[base];            gf1 = gfv[HDIM + base];
      gf2c = gfv[2 * HDIM + base]; gf3 = gfv[3 * HDIM + base];
    }

    bool fin = false;
    for (int t = 0; t < n && !fin; ++t) {
      const int s = sbase + t;
      if (tid < 256) {
        const u64* slot = a.hq + (size_t)(s & 1) * HDIM + tid * 4;
        u64 v0, v1, v2, v3;
        u32 t0, t1, t2, t3;
        int guard = 0;
        for (;;) {
          v0 = __hip_atomic_load(slot + 0, __ATOMIC_RELAXED, __HIP_MEMORY_SCOPE_AGENT);
          v1 = __hip_atomic_load(slot + 1, __ATOMIC_RELAXED, __HIP_MEMORY_SCOPE_AGENT);
          v2 = __hip_atomic_load(slot + 2, __ATOMIC_RELAXED, __HIP_MEMORY_SCOPE_AGENT);
          v3 = __hip_atomic_load(slot + 3, __ATOMIC_RELAXED, __HIP_MEMORY_SCOPE_AGENT);
          t0 = (u32)v0 & 0x7fffffffu; t1 = (u32)v1 & 0x7fffffffu;
          t2 = (u32)v2 & 0x7fffffffu; t3 = (u32)v3 & 0x7fffffffu;
          int ok = (t0 >= (u32)s) && (t1 >= (u32)s) && (t2 >= (u32)s) && (t3 >= (u32)s);
          if (__all(ok)) break;
          if (++guard > 4000000) break;  // anti-hang safety
        }
        int anyg = (t0 > (u32)s) || (t1 > (u32)s) || (t2 > (u32)s) || (t3 > (u32)s);
        int stall = (int)((((u32)v0) >> 31) & (((u32)v1) >> 31) &
                          (((u32)v2) >> 31) & (((u32)v3) >> 31));
        int wany = __any(anyg);
        int wall = __all(stall);
        if (lane == 0) lds_conv[wave] = (wall << 1) | wany;  // waves 0..3 poll
        float4 hv;
        hv.x = __uint_as_float((u32)(v0 >> 32));
        hv.y = __uint_as_float((u32)(v1 >> 32));
        hv.z = __uint_as_float((u32)(v2 >> 32));
        hv.w = __uint_as_float((u32)(v3 >> 32));
        ((float4*)lds_h)[tid] = hv;
      }
      __syncthreads();  // B1
      const int c0 = lds_conv[0], c1 = lds_conv[1], c2 = lds_conv[2], c3 = lds_conv[3];
      const int convdec = ((c0 | c1 | c2 | c3) & 1) | (((c0 & c1 & c2 & c3) >> 1) & 1);

      if (convdec) {
        const int col = tid & 7;
        for (int tt = t + (tid >> 3); tt < n; tt += 64)
          __builtin_nontemporal_store(lds_h8[tt & 1][col],
                                      &hsout[(size_t)tt * HDIM + w * 8 + col]);
        if (lane == 0) {  // wave v publishes its unit's final state
          float hlast = ((n - 1) & 1) ? hp1 : hp0;  // h(n-1)
          float clast = ((n - 1) & 1) ? cp1 : cp0;  // c(n-1)
          cstate = clast;
          u64 pub = (u64)(u32)(sbase + n) | ((u64)__float_as_uint(hlast) << 32);
          __hip_atomic_store(&a.hq[(size_t)((sbase + n) & 1) * HDIM + w * 8 + wave], pub,
                             __ATOMIC_RELAXED, __HIP_MEMORY_SCOPE_AGENT);
        }
        __syncthreads();
        fin = true;
        continue;
      }

      float acc0 = 0.f, acc1 = 0.f;
      const float4* lh4 = (const float4*)lds_h + chunk * 8;
#pragma unroll
      for (int i = 0; i < 8; ++i) {
        float4 h4 = lh4[(i + chunk) & 7];
        acc0 += wreg[0][i].x * h4.x + wreg[0][i].y * h4.y + wreg[0][i].z * h4.z + wreg[0][i].w * h4.w;
        acc1 += wreg[1][i].x * h4.x + wreg[1][i].y * h4.y + wreg[1][i].z * h4.z + wreg[1][i].w * h4.w;
      }
      // 32 chunks of each row live in one half-wave -> butterfly reduce in-register
#pragma unroll
      for (int off = 1; off < 32; off <<= 1) {
        acc0 += __shfl_xor(acc0, off);
        acc1 += __shfl_xor(acc1, off);
      }
      if ((lane & 31) == 0) {
        float2 p; p.x = acc0; p.y = acc1;
        *(float2*)&lds_row[rowgrp * 2] = p;  // rows 2*rowgrp, 2*rowgrp+1
      }
      __syncthreads();  // B2

      if (lane == 0) {  // wave v computes gates for unit v, publishes immediately
        const int v = wave;
        float gi = lds_row[v]      + ((t == tspecial) ? gf0 : gc0);
        float gf = lds_row[8 + v]  + ((t == tspecial) ? gf1 : gc1);
        float gg = lds_row[16 + v] + ((t == tspecial) ? gf2c : gc2);
        float go = lds_row[24 + v] + ((t == tspecial) ? gf3 : gc3);
        float iv = 1.f / (1.f + expf(-gi));
        float fv = 1.f / (1.f + expf(-gf));
        float gv = tanhf(gg);
        float ov = 1.f / (1.f + expf(-go));
        float cnew = fv * cstate + iv * gv;
        float hn = ov * tanhf(cnew);
        float h2 = (t & 1) ? hp1 : hp0;   // h(t-2)
        float c2v = (t & 1) ? cp1 : cp0;  // c(t-2)
        int stab = (fabsf(hn - h2) <= CONV_TOL) &&
                   (fabsf(cnew - c2v) <= CONV_TOL) &&
                   (t > tspecial + 2) && (t >= 32);
        if (t & 1) { hp1 = hn; cp1 = cnew; } else { hp0 = hn; cp0 = cnew; }
        cstate = cnew;
        u32 tagw = (u32)(s + 1) | ((u32)stab << 31);
        u64 pub = (u64)tagw | ((u64)__float_as_uint(hn) << 32);
        __hip_atomic_store(&a.hq[(size_t)((s + 1) & 1) * HDIM + w * 8 + v], pub,
                           __ATOMIC_RELAXED, __HIP_MEMORY_SCOPE_AGENT);
        lds_h8[t & 1][v] = hn;
        __builtin_nontemporal_store(hn, &hsout[(size_t)t * HDIM + w * 8 + v]);
      }
    }
  }
}

// ---------------- lin1_w transpose: L1T[k][j] = lin1_w[j][k] ----------------
__global__ void transpose_kernel(const float* __restrict__ A, float* __restrict__ AT) {
  __shared__ float tile[32][33];
  int j0 = blockIdx.y * 32, k0 = blockIdx.x * 32;
  int tx = threadIdx.x & 31, ty = threadIdx.x >> 5;  // ty 0..7
  for (int r = ty; r < 32; r += 8) tile[r][tx] = A[(size_t)(j0 + r) * HDIM + k0 + tx];
  __syncthreads();
  for (int r = ty; r < 32; r += 8) AT[(size_t)(k0 + r) * HDIM + j0 + tx] = tile[tx][r];
}

// ---------------- beta via tiled GEMM with register-double-buffered K-panels ----------------
// Tile: 128 t x 64 j, K-panels of 32. Grid (n/128, HDIM/64). Each thread: 8t x 4j micro-tile.
__global__ __launch_bounds__(256) void beta_gemm_kernel(
    const float* __restrict__ hsl, const float* __restrict__ hsr,
    const float* __restrict__ L1T, const float* __restrict__ b1,
    const float* __restrict__ u, float* __restrict__ beta) {
  __shared__ float As[32][128];
  __shared__ float Bs[32][64];
  const int tid = threadIdx.x;
  const int t0 = blockIdx.x * 128;
  const int j0 = blockIdx.y * 64;
  const int tm = tid >> 4;       // 0..15 -> rows t0 + tm*8 .. +7
  const int tj = tid & 15;       // 0..15 -> cols j0 + tj*4 .. +3
  const int sr = tid >> 1;       // A-staging row 0..127
  const int sc = (tid & 1) * 4;  // A-staging float4 col base

  float acc[8][4] = {};
  const float4 uv = *(const float4*)(u + j0 + tj * 4);
  const float4 bv = *(const float4*)(b1 + j0 + tj * 4);

  const float4* l4base = (const float4*)(hsl + (size_t)(t0 + sr) * HDIM);
  const float4* r4base = (const float4*)(hsr + (size_t)(t0 + sr) * HDIM);
  const int bkk0 = (tid + 0) >> 4, bjb0 = (tid + 0) & 15;
  const int bkk1 = (tid + 256) >> 4, bjb1 = (tid + 256) & 15;

  float4 ra[4], rb[4], rc0, rc1;
  {  // prologue: panel 0 into registers
#pragma unroll
    for (int i = 0; i < 4; ++i) { ra[i] = l4base[sc + i]; rb[i] = r4base[sc + i]; }
    rc0 = *(const float4*)(L1T + (size_t)bkk0 * HDIM + j0 + bjb0 * 4);
    rc1 = *(const float4*)(L1T + (size_t)bkk1 * HDIM + j0 + bjb1 * 4);
  }

  for (int k0 = 0; k0 < HDIM; k0 += 32) {
    {  // commit registers to LDS
#pragma unroll
      for (int i = 0; i < 4; ++i) {
        As[(sc + i) * 4 + 0][sr] = ra[i].x * rb[i].x;
        As[(sc + i) * 4 + 1][sr] = ra[i].y * rb[i].y;
        As[(sc + i) * 4 + 2][sr] = ra[i].z * rb[i].z;
        As[(sc + i) * 4 + 3][sr] = ra[i].w * rb[i].w;
      }
      *(float4*)&Bs[bkk0][bjb0 * 4] = rc0;
      *(float4*)&Bs[bkk1][bjb1 * 4] = rc1;
    }
    __syncthreads();
    if (k0 + 32 < HDIM) {  // prefetch next panel; vmcnt stays outstanding over compute
      const int kn = (k0 + 32) / 4;
#pragma unroll
      for (int i = 0; i < 4; ++i) { ra[i] = l4base[kn + sc + i]; rb[i] = r4base[kn + sc + i]; }
      rc0 = *(const float4*)(L1T + (size_t)(k0 + 32 + bkk0) * HDIM + j0 + bjb0 * 4);
      rc1 = *(const float4*)(L1T + (size_t)(k0 + 32 + bkk1) * HDIM + j0 + bjb1 * 4);
    }
#pragma unroll
    for (int kk = 0; kk < 32; ++kk) {
      float4 a0 = *(float4*)&As[kk][tm * 8];
      float4 a1 = *(float4*)&As[kk][tm * 8 + 4];
      float4 b = *(float4*)&Bs[kk][tj * 4];
      float ar[8] = {a0.x, a0.y, a0.z, a0.w, a1.x, a1.y, a1.z, a1.w};
      float bc[4] = {b.x, b.y, b.z, b.w};
#pragma unroll
      for (int r = 0; r < 8; ++r)
#pragma unroll
        for (int c = 0; c < 4; ++c) acc[r][c] += ar[r] * bc[c];
    }
    __syncthreads();
  }
  // epilogue: pb[r] = sum_c u[j]*tanh(acc + b1[j]); reduce over the 16 tj lanes; atomicAdd
  float ures[4] = {uv.x, uv.y, uv.z, uv.w};
  float bres[4] = {bv.x, bv.y, bv.z, bv.w};
#pragma unroll
  for (int r = 0; r < 8; ++r) {
    float pb = ures[0] * tanhf(acc[r][0] + bres[0]) + ures[1] * tanhf(acc[r][1] + bres[1]) +
               ures[2] * tanhf(acc[r][2] + bres[2]) + ures[3] * tanhf(acc[r][3] + bres[3]);
#pragma unroll
    for (int off = 1; off < 16; off <<= 1) pb += __shfl_xor(pb, off);
    if (tj == 0) atomicAdd(&beta[t0 + tm * 8 + r], pb);
  }
}

// ---------------- svec with fused softmax: s[h] += sum_t softmax(beta)[t]*O[t][h] ----------------
__global__ __launch_bounds__(256) void svec_kernel(const float* __restrict__ beta,
                                                   const float* __restrict__ hsl,
                                                   const float* __restrict__ hsr,
                                                   float* __restrict__ svec, int n) {
  __shared__ float sm[8];
  __shared__ float wts[256];
  __shared__ float red[4][64];
  const int tid = threadIdx.x, lane = tid & 63, wv = tid >> 6;
  // softmax stats over the full beta (small; L2-broadcast across blocks)
  float m = -3.4e38f;
  for (int i = tid; i < n; i += 256) m = fmaxf(m, beta[i]);
  for (int off = 32; off; off >>= 1) m = fmaxf(m, __shfl_xor(m, off));
  if (lane == 0) sm[wv] = m;
  __syncthreads();
  const float M = fmaxf(fmaxf(sm[0], sm[1]), fmaxf(sm[2], sm[3]));
  float z = 0.f;
  for (int i = tid; i < n; i += 256) z += expf(beta[i] - M);
  for (int off = 32; off; off >>= 1) z += __shfl_xor(z, off);
  if (lane == 0) sm[4 + wv] = z;
  __syncthreads();
  const float invZ = 1.f / (sm[4] + sm[5] + sm[6] + sm[7]);
  const int tlen = n / gridDim.y;   // 256 for n=2048, gridDim.y=8
  const int tbeg = blockIdx.y * tlen;
  for (int i = tid; i < tlen; i += 256) wts[i] = expf(beta[tbeg + i] - M) * invZ;
  __syncthreads();
  const int h = blockIdx.x * 64 + lane;
  const int ts = wv;
  float s = 0.f;
  for (int t = ts; t < tlen; t += 4)
    s += wts[t] * hsl[(size_t)(tbeg + t) * HDIM + h] * hsr[(size_t)(tbeg + t) * HDIM + h];
  red[ts][lane] = s;
  __syncthreads();
  if (tid < 64) {
    float tot = red[0][tid] + red[1][tid] + red[2][tid] + red[3][tid];
    atomicAdd(&svec[blockIdx.x * 64 + tid], tot);
  }
}

// ---------------- out[r] = lin2_w[r] . s + lin2_b[r] ----------------
__global__ void final_kernel(const float* __restrict__ svec, const float* __restrict__ l2w,
                             const float* __restrict__ l2b, float* __restrict__ out) {
  int r = threadIdx.x >> 6, lane = threadIdx.x & 63;
  float s = 0.f;
  for (int k = lane; k < HDIM; k += 64) s += l2w[(size_t)r * HDIM + k] * svec[k];
  for (int off = 32; off; off >>= 1) s += __shfl_xor(s, off);
  if (lane == 0) out[r] = s + l2b[r];
}

extern "C" void kernel_launch(void* const* d_in, const int* in_sizes, int n_in,
                              void* d_out, int out_size, void* d_ws, size_t ws_size,
                              hipStream_t stream) {
  const int* x = (const int*)d_in[0];
  const int* tstart = (const int*)d_in[1];
  const int* tend = (const int*)d_in[2];
  const float* emb = (const float*)d_in[3];
  const float* wih_l = (const float*)d_in[4];
  const float* whh_l = (const float*)d_in[5];
  const float* bih_l = (const float*)d_in[6];
  const float* bhh_l = (const float*)d_in[7];
  const float* wih_r = (const float*)d_in[8];
  const float* whh_r = (const float*)d_in[9];
  const float* bih_r = (const float*)d_in[10];
  const float* bhh_r = (const float*)d_in[11];
  const float* l1w = (const float*)d_in[12];
  const float* l1b = (const float*)d_in[13];
  const float* u = (const float*)d_in[14];
  const float* l2w = (const float*)d_in[15];
  const float* l2b = (const float*)d_in[16];
  const int n = in_sizes[0];  // 2048
  (void)n_in; (void)out_size; (void)ws_size;

  float* ws = (float*)d_ws;
  float* target = ws;                     // 1024
  float* seqfl = ws + 1024;               // 1024
  float* seqfr = ws + 2048;               // 1024
  float* glc = ws + 3072;                 // 4096
  float* glf = glc + 4096;                // 4096
  float* grc = glf + 4096;                // 4096
  float* grf = grc + 4096;                // 4096
  u64* hq = (u64*)(grf + 4096);           // 2*1024 u64 (8B aligned)
  float* hsl = (float*)(hq + 2 * HDIM);   // n*1024
  float* hsr = hsl + (size_t)n * HDIM;    // n*1024
  float* L1T = hsr + (size_t)n * HDIM;    // 1024*1024
  float* beta = L1T + (size_t)HDIM * HDIM;  // n
  float* svec = beta + n;                 // 1024

  setup_kernel<<<1, 1024, 0, stream>>>(x, tstart, tend, emb, target, seqfl, seqfr, hq,
                                       beta, svec, n);
  gateconst_kernel<<<dim3(1024, 2), 256, 0, stream>>>(wih_l, bih_l, bhh_l, wih_r, bih_r, bhh_r,
                                                      target, seqfl, seqfr, glc, glf, grc, grf);
  RecArgs ra;
  ra.whh_l = whh_l; ra.whh_r = whh_r;
  ra.glc = glc; ra.glf = glf; ra.grc = grc; ra.grf = grf;
  ra.hq = hq; ra.hsl = hsl; ra.hsr = hsr;
  ra.pstart = tstart; ra.pend = tend; ra.n = n;
  // Plain launch: the kernel's tag-based sync only needs co-residency, and
  // 128 WGs x 8 waves = 1024 waves <= device capacity (256 CU x 32 waves),
  // so all WGs are always resident. Avoids cooperative-dispatch overhead.
  rec_kernel<<<dim3(NWG), dim3(TPB), 0, stream>>>(ra);

  transpose_kernel<<<dim3(32, 32), 256, 0, stream>>>(l1w, L1T);
  beta_gemm_kernel<<<dim3(n / 128, HDIM / 64), 256, 0, stream>>>(hsl, hsr, L1T, l1b, u, beta);
  svec_kernel<<<dim3(16, 8), 256, 0, stream>>>(beta, hsl, hsr, svec, n);
  final_kernel<<<1, 192, 0, stream>>>(svec, l2w, l2b, (float*)d_out);
}

// Round 6
// 816.533 us; speedup vs baseline: 1.4985x; 1.4985x over previous
//
#include <hip/hip_runtime.h>
#include <math.h>

#define HDIM 1024
#define NWG 128
#define TPB 256
#define CONV_TOL 1.0e-5f

typedef unsigned long long u64;
typedef unsigned int u32;

struct RecArgs {
  const float* whh_l; const float* whh_r;
  const float* glc; const float* glf; const float* grc; const float* grf;
  u64* hq;            // [2][HDIM] tagged slots: low32 = tag | stable<<31, high32 = f32 bits
  float* hsl;         // [n][HDIM]
  float* hsr;         // [n][HDIM]
  const int* pstart; const int* pend;
  int n;
};

// ---------------- setup: target vector, special rows, tagged-state init, accum zeroing ----------------
__global__ void setup_kernel(const int* __restrict__ x, const int* ts, const int* te,
                             const float* __restrict__ emb,
                             float* target, float* seqfl, float* seqfr,
                             u64* hq, float* beta, float* svec, int n) {
  int e = threadIdx.x;  // 0..1023
  int start = ts[0], end = te[0];
  int first_l = (start > 0) ? 0 : (end + 1);
  int first_r = (end < n - 1) ? (n - 1) : (start - 1);
  int fl = min(max(first_l, 0), n - 1);
  int fr = min(max(first_r, 0), n - 1);
  float sum = 0.f;
  for (int p = start; p <= end; ++p) sum += emb[(size_t)x[p] * HDIM + e];
  target[e] = sum / (float)(end - start + 1);
  seqfl[e] = emb[(size_t)x[fl] * HDIM + e];
  seqfr[e] = emb[(size_t)x[fr] * HDIM + e];
  // tag=0 (h input for step 0), value = 0.0f, stable=0 — both parities
  hq[e] = 0ull;
  hq[HDIM + e] = 0ull;
  for (int i = e; i < n; i += 1024) beta[i] = 0.f;
  svec[e] = 0.f;
}

// ---------------- gate-constant vectors: w_ih@v + b_ih + b_hh ----------------
__global__ __launch_bounds__(256) void gateconst_kernel(
    const float* __restrict__ wih_l, const float* bih_l, const float* bhh_l,
    const float* __restrict__ wih_r, const float* bih_r, const float* bhh_r,
    const float* __restrict__ target, const float* __restrict__ seqfl,
    const float* __restrict__ seqfr,
    float* glc, float* glf, float* grc, float* grf) {
  int side = blockIdx.y;
  const float* wih = side ? wih_r : wih_l;
  const float* bih = side ? bih_r : bih_l;
  const float* bhh = side ? bhh_r : bhh_l;
  const float* sf = side ? seqfr : seqfl;
  float* outc = side ? grc : glc;
  float* outf = side ? grf : glf;
  int wv = threadIdx.x >> 6, lane = threadIdx.x & 63;
  int r = blockIdx.x * 4 + wv;  // 0..4095
  const float4* wrow = (const float4*)(wih + (size_t)r * HDIM);
  const float4* tg4 = (const float4*)target;
  const float4* sf4 = (const float4*)sf;
  float dc = 0.f, df = 0.f;
#pragma unroll
  for (int k = 0; k < 4; ++k) {
    float4 w4 = wrow[lane + 64 * k];
    float4 t4 = tg4[lane + 64 * k];
    float4 s4 = sf4[lane + 64 * k];
    dc += w4.x * t4.x + w4.y * t4.y + w4.z * t4.z + w4.w * t4.w;
    df += w4.x * s4.x + w4.y * s4.y + w4.z * s4.z + w4.w * s4.w;
  }
  for (int off = 32; off; off >>= 1) {
    dc += __shfl_xor(dc, off);
    df += __shfl_xor(df, off);
  }
  if (lane == 0) {
    float bb = bih[r] + bhh[r];
    outc[r] = dc + bb;
    outf[r] = df + bb;
  }
}

// ---------------- persistent recurrence ----------------
// REVERTED to the 440us structure (TPB=256, lds_part staging, wave0-only gate compute,
// SINGLE-WAVE coalesced publish from lanes<8 — the critical property; Round-1's
// distributed 8-wave publish regressed 440->808us from publish jitter + lost coalescing).
// Deltas vs the 440us kernel, all inside wave0's post-B2 epilogue:
//  (1) 32-term column sum split across 64 lanes (16 terms/lane + shfl_xor(32) merge)
//  (2) gate nonlinearities computed in parallel across 32 lanes (one exp chain w/ select,
//      tanh via clamped (1-e)/(1+e)) instead of 4 serial transcendental chains in 8 lanes
//  (3) hq publish issued BEFORE lds_h8/hsout stores
__global__ __launch_bounds__(TPB, 1) void rec_kernel(RecArgs a) {
  const int w = blockIdx.x;
  const int tid = threadIdx.x;
  const int wave = tid >> 6;
  const int lane = tid & 63;
  const int chunk = tid & 31;    // 32-col chunk of the k dimension
  const int rowgrp = tid >> 5;   // 0..7 -> local rows rowgrp*4..+3
  const int n = a.n;

  __shared__ float lds_h[HDIM];
  __shared__ float lds_part[32 * 36];  // [chunk][row] pitch 36 floats (16B-aligned rows)
  __shared__ float lds_h8[2][8];       // [local parity][unit]
  __shared__ int lds_conv[4];

  const int start = a.pstart[0];
  const int end = a.pend[0];
  const int first_l = (start > 0) ? 0 : (end + 1);
  const int first_r = (end < n - 1) ? (n - 1) : (start - 1);

  float4 wreg[4][8];  // constant-indexed only => guaranteed VGPR residency
  float cstate = 0.f;
  float hp0 = 0.f, hp1 = 0.f, cp0 = 0.f, cp1 = 0.f;  // parity history

  for (int pass = 0; pass < 2; ++pass) {
    const float* whh = pass ? a.whh_r : a.whh_l;
    const float* gcv = pass ? a.grc : a.glc;
    const float* gfv = pass ? a.grf : a.glf;
    float* hsout = pass ? a.hsr : a.hsl;
    const int tspecial = pass ? (n - 1 - first_r) : first_l;
    const int sbase = pass * n;

#pragma unroll
    for (int r = 0; r < 4; ++r) {
      const int lr = rowgrp * 4 + r;
      const int grow = (lr >> 3) * HDIM + w * 8 + (lr & 7);
      const float4* wr = (const float4*)(whh + (size_t)grow * HDIM) + chunk * 8;
#pragma unroll
      for (int i = 0; i < 8; ++i) wreg[r][i] = wr[(i + chunk) & 7];
    }
    // gate constants for wave0's gate-row mapping: r32 = lane&31 -> gate r32>>3, unit r32&7.
    // Loaded on BOTH 32-lane halves (same value) so the post-merge add works on all lanes.
    float my_gc = 0.f, my_gf = 0.f;
    if (wave == 0) {
      const int r32 = lane & 31;
      const int R = (r32 >> 3) * HDIM + w * 8 + (r32 & 7);
      my_gc = gcv[R];
      my_gf = gfv[R];
    }

    bool fin = false;
    for (int t = 0; t < n && !fin; ++t) {
      const int s = sbase + t;
      const u64* slot = a.hq + (size_t)(s & 1) * HDIM + tid * 4;
      u64 v0, v1, v2, v3;
      u32 t0, t1, t2, t3;
      int guard = 0;
      for (;;) {
        v0 = __hip_atomic_load(slot + 0, __ATOMIC_RELAXED, __HIP_MEMORY_SCOPE_AGENT);
        v1 = __hip_atomic_load(slot + 1, __ATOMIC_RELAXED, __HIP_MEMORY_SCOPE_AGENT);
        v2 = __hip_atomic_load(slot + 2, __ATOMIC_RELAXED, __HIP_MEMORY_SCOPE_AGENT);
        v3 = __hip_atomic_load(slot + 3, __ATOMIC_RELAXED, __HIP_MEMORY_SCOPE_AGENT);
        t0 = (u32)v0 & 0x7fffffffu; t1 = (u32)v1 & 0x7fffffffu;
        t2 = (u32)v2 & 0x7fffffffu; t3 = (u32)v3 & 0x7fffffffu;
        int ok = (t0 >= (u32)s) && (t1 >= (u32)s) && (t2 >= (u32)s) && (t3 >= (u32)s);
        if (__all(ok)) break;
        if (++guard > 4000000) break;  // anti-hang safety
      }
      int anyg = (t0 > (u32)s) || (t1 > (u32)s) || (t2 > (u32)s) || (t3 > (u32)s);
      int stall = (int)((((u32)v0) >> 31) & (((u32)v1) >> 31) &
                        (((u32)v2) >> 31) & (((u32)v3) >> 31));
      int wany = __any(anyg);
      int wall = __all(stall);
      if (lane == 0) lds_conv[wave] = (wall << 1) | wany;
      float4 hv;
      hv.x = __uint_as_float((u32)(v0 >> 32));
      hv.y = __uint_as_float((u32)(v1 >> 32));
      hv.z = __uint_as_float((u32)(v2 >> 32));
      hv.w = __uint_as_float((u32)(v3 >> 32));
      ((float4*)lds_h)[tid] = hv;
      __syncthreads();  // B1
      const int c0 = lds_conv[0], c1 = lds_conv[1], c2 = lds_conv[2], c3 = lds_conv[3];
      const int convdec = ((c0 | c1 | c2 | c3) & 1) | (((c0 & c1 & c2 & c3) >> 1) & 1);

      if (convdec) {
        const int col = tid & 7;
        for (int tt = t + (tid >> 3); tt < n; tt += 32)
          __builtin_nontemporal_store(lds_h8[tt & 1][col],
                                      &hsout[(size_t)tt * HDIM + w * 8 + col]);
        if (wave == 0 && lane < 8) {
          float hlast = ((n - 1) & 1) ? hp1 : hp0;  // h(n-1)
          float clast = ((n - 1) & 1) ? cp1 : cp0;  // c(n-1)
          cstate = clast;
          u64 pub = (u64)(u32)(sbase + n) | ((u64)__float_as_uint(hlast) << 32);
          __hip_atomic_store(&a.hq[(size_t)((sbase + n) & 1) * HDIM + w * 8 + lane], pub,
                             __ATOMIC_RELAXED, __HIP_MEMORY_SCOPE_AGENT);
        }
        __syncthreads();
        fin = true;
        continue;
      }

      float acc0 = 0.f, acc1 = 0.f, acc2 = 0.f, acc3 = 0.f;
      const float4* lh4 = (const float4*)lds_h + chunk * 8;
#pragma unroll
      for (int i = 0; i < 8; ++i) {
        float4 h4 = lh4[(i + chunk) & 7];
        acc0 += wreg[0][i].x * h4.x + wreg[0][i].y * h4.y + wreg[0][i].z * h4.z + wreg[0][i].w * h4.w;
        acc1 += wreg[1][i].x * h4.x + wreg[1][i].y * h4.y + wreg[1][i].z * h4.z + wreg[1][i].w * h4.w;
        acc2 += wreg[2][i].x * h4.x + wreg[2][i].y * h4.y + wreg[2][i].z * h4.z + wreg[2][i].w * h4.w;
        acc3 += wreg[3][i].x * h4.x + wreg[3][i].y * h4.y + wreg[3][i].z * h4.z + wreg[3][i].w * h4.w;
      }
      {
        float4 p; p.x = acc0; p.y = acc1; p.z = acc2; p.w = acc3;
        *(float4*)&lds_part[chunk * 36 + rowgrp * 4] = p;
      }
      __syncthreads();  // B2

      if (wave == 0) {
        // (1) split reduce: half lanes sum cc 0..15, other half cc 16..31, merge via xor-32
        const int r32 = lane & 31;
        const int ccb = (lane >> 5) * 16;
        float sum = 0.f;
#pragma unroll
        for (int cc = 0; cc < 16; ++cc) sum += lds_part[(ccb + cc) * 36 + r32];
        sum += __shfl_xor(sum, 32);
        sum += (t == tspecial) ? my_gf : my_gc;
        // (2) parallel nonlinearity: gate = r32>>3 (0=i,1=f,2=g(tanh),3=o)
        const bool is_t = ((r32 >> 3) == 2);
        float xx = is_t ? fminf(fmaxf(sum + sum, -30.f), 30.f) : sum;
        float e = expf(-xx);
        float num = is_t ? (1.f - e) : 1.f;
        float act = num / (1.f + e);
        const int j = lane & 7;
        float iv = __shfl(act, j);
        float fv = __shfl(act, 8 + j);
        float gv = __shfl(act, 16 + j);
        float ov = __shfl(act, 24 + j);
        if (lane < 8) {
          float cnew = fv * cstate + iv * gv;
          float hn = ov * tanhf(cnew);
          float h2 = (t & 1) ? hp1 : hp0;   // h(t-2)
          float c2v = (t & 1) ? cp1 : cp0;  // c(t-2)
          int stab = (fabsf(hn - h2) <= CONV_TOL) &&
                     (fabsf(cnew - c2v) <= CONV_TOL) &&
                     (t > tspecial + 2) && (t >= 32);
          if (t & 1) { hp1 = hn; cp1 = cnew; } else { hp0 = hn; cp0 = cnew; }
          cstate = cnew;
          // (3) publish FIRST — single-wave coalesced 64B publish, the critical property
          u32 tagw = (u32)(s + 1) | ((u32)stab << 31);
          u64 pub = (u64)tagw | ((u64)__float_as_uint(hn) << 32);
          __hip_atomic_store(&a.hq[(size_t)((s + 1) & 1) * HDIM + w * 8 + j], pub,
                             __ATOMIC_RELAXED, __HIP_MEMORY_SCOPE_AGENT);
          lds_h8[t & 1][j] = hn;
          __builtin_nontemporal_store(hn, &hsout[(size_t)t * HDIM + w * 8 + j]);
        }
      }
    }
  }
}

// ---------------- lin1_w transpose: L1T[k][j] = lin1_w[j][k] ----------------
__global__ void transpose_kernel(const float* __restrict__ A, float* __restrict__ AT) {
  __shared__ float tile[32][33];
  int j0 = blockIdx.y * 32, k0 = blockIdx.x * 32;
  int tx = threadIdx.x & 31, ty = threadIdx.x >> 5;  // ty 0..7
  for (int r = ty; r < 32; r += 8) tile[r][tx] = A[(size_t)(j0 + r) * HDIM + k0 + tx];
  __syncthreads();
  for (int r = ty; r < 32; r += 8) AT[(size_t)(k0 + r) * HDIM + j0 + tx] = tile[tx][r];
}

// ---------------- beta via tiled GEMM with register-double-buffered K-panels ----------------
// Tile: 128 t x 64 j, K-panels of 32. Grid (n/128, HDIM/64). Each thread: 8t x 4j micro-tile.
__global__ __launch_bounds__(256) void beta_gemm_kernel(
    const float* __restrict__ hsl, const float* __restrict__ hsr,
    const float* __restrict__ L1T, const float* __restrict__ b1,
    const float* __restrict__ u, float* __restrict__ beta) {
  __shared__ float As[32][128];
  __shared__ float Bs[32][64];
  const int tid = threadIdx.x;
  const int t0 = blockIdx.x * 128;
  const int j0 = blockIdx.y * 64;
  const int tm = tid >> 4;       // 0..15 -> rows t0 + tm*8 .. +7
  const int tj = tid & 15;       // 0..15 -> cols j0 + tj*4 .. +3
  const int sr = tid >> 1;       // A-staging row 0..127
  const int sc = (tid & 1) * 4;  // A-staging float4 col base

  float acc[8][4] = {};
  const float4 uv = *(const float4*)(u + j0 + tj * 4);
  const float4 bv = *(const float4*)(b1 + j0 + tj * 4);

  const float4* l4base = (const float4*)(hsl + (size_t)(t0 + sr) * HDIM);
  const float4* r4base = (const float4*)(hsr + (size_t)(t0 + sr) * HDIM);
  const int bkk0 = (tid + 0) >> 4, bjb0 = (tid + 0) & 15;
  const int bkk1 = (tid + 256) >> 4, bjb1 = (tid + 256) & 15;

  float4 ra[4], rb[4], rc0, rc1;
  {  // prologue: panel 0 into registers
#pragma unroll
    for (int i = 0; i < 4; ++i) { ra[i] = l4base[sc + i]; rb[i] = r4base[sc + i]; }
    rc0 = *(const float4*)(L1T + (size_t)bkk0 * HDIM + j0 + bjb0 * 4);
    rc1 = *(const float4*)(L1T + (size_t)bkk1 * HDIM + j0 + bjb1 * 4);
  }

  for (int k0 = 0; k0 < HDIM; k0 += 32) {
    {  // commit registers to LDS
#pragma unroll
      for (int i = 0; i < 4; ++i) {
        As[(sc + i) * 4 + 0][sr] = ra[i].x * rb[i].x;
        As[(sc + i) * 4 + 1][sr] = ra[i].y * rb[i].y;
        As[(sc + i) * 4 + 2][sr] = ra[i].z * rb[i].z;
        As[(sc + i) * 4 + 3][sr] = ra[i].w * rb[i].w;
      }
      *(float4*)&Bs[bkk0][bjb0 * 4] = rc0;
      *(float4*)&Bs[bkk1][bjb1 * 4] = rc1;
    }
    __syncthreads();
    if (k0 + 32 < HDIM) {  // prefetch next panel; vmcnt stays outstanding over compute
      const int kn = (k0 + 32) / 4;
#pragma unroll
      for (int i = 0; i < 4; ++i) { ra[i] = l4base[kn + sc + i]; rb[i] = r4base[kn + sc + i]; }
      rc0 = *(const float4*)(L1T + (size_t)(k0 + 32 + bkk0) * HDIM + j0 + bjb0 * 4);
      rc1 = *(const float4*)(L1T + (size_t)(k0 + 32 + bkk1) * HDIM + j0 + bjb1 * 4);
    }
#pragma unroll
    for (int kk = 0; kk < 32; ++kk) {
      float4 a0 = *(float4*)&As[kk][tm * 8];
      float4 a1 = *(float4*)&As[kk][tm * 8 + 4];
      float4 b = *(float4*)&Bs[kk][tj * 4];
      float ar[8] = {a0.x, a0.y, a0.z, a0.w, a1.x, a1.y, a1.z, a1.w};
      float bc[4] = {b.x, b.y, b.z, b.w};
#pragma unroll
      for (int r = 0; r < 8; ++r)
#pragma unroll
        for (int c = 0; c < 4; ++c) acc[r][c] += ar[r] * bc[c];
    }
    __syncthreads();
  }
  // epilogue: pb[r] = sum_c u[j]*tanh(acc + b1[j]); reduce over the 16 tj lanes; atomicAdd
  float ures[4] = {uv.x, uv.y, uv.z, uv.w};
  float bres[4] = {bv.x, bv.y, bv.z, bv.w};
#pragma unroll
  for (int r = 0; r < 8; ++r) {
    float pb = ures[0] * tanhf(acc[r][0] + bres[0]) + ures[1] * tanhf(acc[r][1] + bres[1]) +
               ures[2] * tanhf(acc[r][2] + bres[2]) + ures[3] * tanhf(acc[r][3] + bres[3]);
#pragma unroll
    for (int off = 1; off < 16; off <<= 1) pb += __shfl_xor(pb, off);
    if (tj == 0) atomicAdd(&beta[t0 + tm * 8 + r], pb);
  }
}

// ---------------- svec with fused softmax: s[h] += sum_t softmax(beta)[t]*O[t][h] ----------------
__global__ __launch_bounds__(256) void svec_kernel(const float* __restrict__ beta,
                                                   const float* __restrict__ hsl,
                                                   const float* __restrict__ hsr,
                                                   float* __restrict__ svec, int n) {
  __shared__ float sm[8];
  __shared__ float wts[256];
  __shared__ float red[4][64];
  const int tid = threadIdx.x, lane = tid & 63, wv = tid >> 6;
  // softmax stats over the full beta (small; L2-broadcast across blocks)
  float m = -3.4e38f;
  for (int i = tid; i < n; i += 256) m = fmaxf(m, beta[i]);
  for (int off = 32; off; off >>= 1) m = fmaxf(m, __shfl_xor(m, off));
  if (lane == 0) sm[wv] = m;
  __syncthreads();
  const float M = fmaxf(fmaxf(sm[0], sm[1]), fmaxf(sm[2], sm[3]));
  float z = 0.f;
  for (int i = tid; i < n; i += 256) z += expf(beta[i] - M);
  for (int off = 32; off; off >>= 1) z += __shfl_xor(z, off);
  if (lane == 0) sm[4 + wv] = z;
  __syncthreads();
  const float invZ = 1.f / (sm[4] + sm[5] + sm[6] + sm[7]);
  const int tlen = n / gridDim.y;   // 256 for n=2048, gridDim.y=8
  const int tbeg = blockIdx.y * tlen;
  for (int i = tid; i < tlen; i += 256) wts[i] = expf(beta[tbeg + i] - M) * invZ;
  __syncthreads();
  const int h = blockIdx.x * 64 + lane;
  const int ts = wv;
  float s = 0.f;
  for (int t = ts; t < tlen; t += 4)
    s += wts[t] * hsl[(size_t)(tbeg + t) * HDIM + h] * hsr[(size_t)(tbeg + t) * HDIM + h];
  red[ts][lane] = s;
  __syncthreads();
  if (tid < 64) {
    float tot = red[0][tid] + red[1][tid] + red[2][tid] + red[3][tid];
    atomicAdd(&svec[blockIdx.x * 64 + tid], tot);
  }
}

// ---------------- out[r] = lin2_w[r] . s + lin2_b[r] ----------------
__global__ void final_kernel(const float* __restrict__ svec, const float* __restrict__ l2w,
                             const float* __restrict__ l2b, float* __restrict__ out) {
  int r = threadIdx.x >> 6, lane = threadIdx.x & 63;
  float s = 0.f;
  for (int k = lane; k < HDIM; k += 64) s += l2w[(size_t)r * HDIM + k] * svec[k];
  for (int off = 32; off; off >>= 1) s += __shfl_xor(s, off);
  if (lane == 0) out[r] = s + l2b[r];
}

extern "C" void kernel_launch(void* const* d_in, const int* in_sizes, int n_in,
                              void* d_out, int out_size, void* d_ws, size_t ws_size,
                              hipStream_t stream) {
  const int* x = (const int*)d_in[0];
  const int* tstart = (const int*)d_in[1];
  const int* tend = (const int*)d_in[2];
  const float* emb = (const float*)d_in[3];
  const float* wih_l = (const float*)d_in[4];
  const float* whh_l = (const float*)d_in[5];
  const float* bih_l = (const float*)d_in[6];
  const float* bhh_l = (const float*)d_in[7];
  const float* wih_r = (const float*)d_in[8];
  const float* whh_r = (const float*)d_in[9];
  const float* bih_r = (const float*)d_in[10];
  const float* bhh_r = (const float*)d_in[11];
  const float* l1w = (const float*)d_in[12];
  const float* l1b = (const float*)d_in[13];
  const float* u = (const float*)d_in[14];
  const float* l2w = (const float*)d_in[15];
  const float* l2b = (const float*)d_in[16];
  const int n = in_sizes[0];  // 2048
  (void)n_in; (void)out_size; (void)ws_size;

  float* ws = (float*)d_ws;
  float* target = ws;                     // 1024
  float* seqfl = ws + 1024;               // 1024
  float* seqfr = ws + 2048;               // 1024
  float* glc = ws + 3072;                 // 4096
  float* glf = glc + 4096;                // 4096
  float* grc = glf + 4096;                // 4096
  float* grf = grc + 4096;                // 4096
  u64* hq = (u64*)(grf + 4096);           // 2*1024 u64 (8B aligned)
  float* hsl = (float*)(hq + 2 * HDIM);   // n*1024
  float* hsr = hsl + (size_t)n * HDIM;    // n*1024
  float* L1T = hsr + (size_t)n * HDIM;    // 1024*1024
  float* beta = L1T + (size_t)HDIM * HDIM;  // n
  float* svec = beta + n;                 // 1024

  setup_kernel<<<1, 1024, 0, stream>>>(x, tstart, tend, emb, target, seqfl, seqfr, hq,
                                       beta, svec, n);
  gateconst_kernel<<<dim3(1024, 2), 256, 0, stream>>>(wih_l, bih_l, bhh_l, wih_r, bih_r, bhh_r,
                                                      target, seqfl, seqfr, glc, glf, grc, grf);
  RecArgs ra;
  ra.whh_l = whh_l; ra.whh_r = whh_r;
  ra.glc = glc; ra.glf = glf; ra.grc = grc; ra.grf = grf;
  ra.hq = hq; ra.hsl = hsl; ra.hsr = hsr;
  ra.pstart = tstart; ra.pend = tend; ra.n = n;
  // Plain launch (kept from Round 1: non-rec time 451->416us). Co-residency is
  // trivially guaranteed: 128 WGs x 4 waves = 512 waves << 8192 device capacity.
  rec_kernel<<<dim3(NWG), dim3(TPB), 0, stream>>>(ra);

  transpose_kernel<<<dim3(32, 32), 256, 0, stream>>>(l1w, L1T);
  beta_gemm_kernel<<<dim3(n / 128, HDIM / 64), 256, 0, stream>>>(hsl, hsr, L1T, l1b, u, beta);
  svec_kernel<<<dim3(16, 8), 256, 0, stream>>>(beta, hsl, hsr, svec, n);
  final_kernel<<<1, 192, 0, stream>>>(svec, l2w, l2b, (float*)d_out);
}

// Round 8
// 815.480 us; speedup vs baseline: 1.5004x; 1.0013x over previous
//
#include <hip/hip_runtime.h>
#include <math.h>

#define HDIM 1024
#define NWG 128
#define TPB 256
#define CONV_TOL 1.0e-5f

typedef unsigned long long u64;
typedef unsigned int u32;

struct RecArgs {
  const float* whh_l; const float* whh_r;
  const float* glc; const float* glf; const float* grc; const float* grf;
  u64* hq;            // [2][HDIM] tagged slots: low32 = tag | stable<<31, high32 = f32 bits
  float* hsl;         // [n][HDIM]
  float* hsr;         // [n][HDIM]
  const int* pstart; const int* pend;
  int n;
};

// ---------------- setup: target vector, special rows, tagged-state init, accum zeroing ----------------
__global__ void setup_kernel(const int* __restrict__ x, const int* ts, const int* te,
                             const float* __restrict__ emb,
                             float* target, float* seqfl, float* seqfr,
                             u64* hq, float* beta, float* svec, int n) {
  int e = threadIdx.x;  // 0..1023
  int start = ts[0], end = te[0];
  int first_l = (start > 0) ? 0 : (end + 1);
  int first_r = (end < n - 1) ? (n - 1) : (start - 1);
  int fl = min(max(first_l, 0), n - 1);
  int fr = min(max(first_r, 0), n - 1);
  float sum = 0.f;
  for (int p = start; p <= end; ++p) sum += emb[(size_t)x[p] * HDIM + e];
  target[e] = sum / (float)(end - start + 1);
  seqfl[e] = emb[(size_t)x[fl] * HDIM + e];
  seqfr[e] = emb[(size_t)x[fr] * HDIM + e];
  // tag=0 (h input for step 0), value = 0.0f, stable=0 — both parities
  hq[e] = 0ull;
  hq[HDIM + e] = 0ull;
  for (int i = e; i < n; i += 1024) beta[i] = 0.f;
  svec[e] = 0.f;
}

// ---------------- gate-constant vectors: w_ih@v + b_ih + b_hh ----------------
__global__ __launch_bounds__(256) void gateconst_kernel(
    const float* __restrict__ wih_l, const float* bih_l, const float* bhh_l,
    const float* __restrict__ wih_r, const float* bih_r, const float* bhh_r,
    const float* __restrict__ target, const float* __restrict__ seqfl,
    const float* __restrict__ seqfr,
    float* glc, float* glf, float* grc, float* grf) {
  int side = blockIdx.y;
  const float* wih = side ? wih_r : wih_l;
  const float* bih = side ? bih_r : bih_l;
  const float* bhh = side ? bhh_r : bhh_l;
  const float* sf = side ? seqfr : seqfl;
  float* outc = side ? grc : glc;
  float* outf = side ? grf : glf;
  int wv = threadIdx.x >> 6, lane = threadIdx.x & 63;
  int r = blockIdx.x * 4 + wv;  // 0..4095
  const float4* wrow = (const float4*)(wih + (size_t)r * HDIM);
  const float4* tg4 = (const float4*)target;
  const float4* sf4 = (const float4*)sf;
  float dc = 0.f, df = 0.f;
#pragma unroll
  for (int k = 0; k < 4; ++k) {
    float4 w4 = wrow[lane + 64 * k];
    float4 t4 = tg4[lane + 64 * k];
    float4 s4 = sf4[lane + 64 * k];
    dc += w4.x * t4.x + w4.y * t4.y + w4.z * t4.z + w4.w * t4.w;
    df += w4.x * s4.x + w4.y * s4.y + w4.z * s4.z + w4.w * s4.w;
  }
  for (int off = 32; off; off >>= 1) {
    dc += __shfl_xor(dc, off);
    df += __shfl_xor(df, off);
  }
  if (lane == 0) {
    float bb = bih[r] + bhh[r];
    outc[r] = dc + bb;
    outf[r] = df + bb;
  }
}

// ---------------- persistent recurrence ----------------
// 440us structure (TPB=256, lds_part staging, wave0 gate compute, single-wave coalesced
// publish) + R6 epilogue parallelization (measured 400us). R7 deltas:
//  (a) PREDICATED POLLING: a lane stops re-loading slots once its tags >= s. Equivalent:
//      while any WG polls step s, ready slots are frozen (1-step-lag protocol forbids
//      overwrite at s+2 until all WGs leave step s), so stale snapshot == fresh read.
//      Cuts spin-time LLC read pressure ~5-10x (128 WGs x 8KB/sweep while waiting).
//  (b) pairwise tree for the 16-term epilogue sum (shorter serial FP-add chain).
__global__ __launch_bounds__(TPB, 1) void rec_kernel(RecArgs a) {
  const int w = blockIdx.x;
  const int tid = threadIdx.x;
  const int wave = tid >> 6;
  const int lane = tid & 63;
  const int chunk = tid & 31;    // 32-col chunk of the k dimension
  const int rowgrp = tid >> 5;   // 0..7 -> local rows rowgrp*4..+3
  const int n = a.n;

  __shared__ float lds_h[HDIM];
  __shared__ float lds_part[32 * 36];  // [chunk][row] pitch 36 floats (16B-aligned rows)
  __shared__ float lds_h8[2][8];       // [local parity][unit]
  __shared__ int lds_conv[4];

  const int start = a.pstart[0];
  const int end = a.pend[0];
  const int first_l = (start > 0) ? 0 : (end + 1);
  const int first_r = (end < n - 1) ? (n - 1) : (start - 1);

  float4 wreg[4][8];  // constant-indexed only => guaranteed VGPR residency
  float cstate = 0.f;
  float hp0 = 0.f, hp1 = 0.f, cp0 = 0.f, cp1 = 0.f;  // parity history

  for (int pass = 0; pass < 2; ++pass) {
    const float* whh = pass ? a.whh_r : a.whh_l;
    const float* gcv = pass ? a.grc : a.glc;
    const float* gfv = pass ? a.grf : a.glf;
    float* hsout = pass ? a.hsr : a.hsl;
    const int tspecial = pass ? (n - 1 - first_r) : first_l;
    const int sbase = pass * n;

#pragma unroll
    for (int r = 0; r < 4; ++r) {
      const int lr = rowgrp * 4 + r;
      const int grow = (lr >> 3) * HDIM + w * 8 + (lr & 7);
      const float4* wr = (const float4*)(whh + (size_t)grow * HDIM) + chunk * 8;
#pragma unroll
      for (int i = 0; i < 8; ++i) wreg[r][i] = wr[(i + chunk) & 7];
    }
    // gate constants for wave0's gate-row mapping: r32 = lane&31 -> gate r32>>3, unit r32&7.
    // Loaded on BOTH 32-lane halves (same value) so the post-merge add works on all lanes.
    float my_gc = 0.f, my_gf = 0.f;
    if (wave == 0) {
      const int r32 = lane & 31;
      const int R = (r32 >> 3) * HDIM + w * 8 + (r32 & 7);
      my_gc = gcv[R];
      my_gf = gfv[R];
    }

    bool fin = false;
    for (int t = 0; t < n && !fin; ++t) {
      const int s = sbase + t;
      const u64* slot = a.hq + (size_t)(s & 1) * HDIM + tid * 4;
      u64 v0 = 0, v1 = 0, v2 = 0, v3 = 0;
      u32 t0 = 0, t1 = 0, t2 = 0, t3 = 0;
      int done = 0;
      int guard = 0;
      for (;;) {
        if (!done) {  // predicated: ready lanes stop hammering the LLC
          v0 = __hip_atomic_load(slot + 0, __ATOMIC_RELAXED, __HIP_MEMORY_SCOPE_AGENT);
          v1 = __hip_atomic_load(slot + 1, __ATOMIC_RELAXED, __HIP_MEMORY_SCOPE_AGENT);
          v2 = __hip_atomic_load(slot + 2, __ATOMIC_RELAXED, __HIP_MEMORY_SCOPE_AGENT);
          v3 = __hip_atomic_load(slot + 3, __ATOMIC_RELAXED, __HIP_MEMORY_SCOPE_AGENT);
          t0 = (u32)v0 & 0x7fffffffu; t1 = (u32)v1 & 0x7fffffffu;
          t2 = (u32)v2 & 0x7fffffffu; t3 = (u32)v3 & 0x7fffffffu;
          done = (t0 >= (u32)s) && (t1 >= (u32)s) && (t2 >= (u32)s) && (t3 >= (u32)s);
        }
        if (__all(done)) break;
        if (++guard > 4000000) break;  // anti-hang safety
      }
      int anyg = (t0 > (u32)s) || (t1 > (u32)s) || (t2 > (u32)s) || (t3 > (u32)s);
      int stall = (int)((((u32)v0) >> 31) & (((u32)v1) >> 31) &
                        (((u32)v2) >> 31) & (((u32)v3) >> 31));
      int wany = __any(anyg);
      int wall = __all(stall);
      if (lane == 0) lds_conv[wave] = (wall << 1) | wany;
      float4 hv;
      hv.x = __uint_as_float((u32)(v0 >> 32));
      hv.y = __uint_as_float((u32)(v1 >> 32));
      hv.z = __uint_as_float((u32)(v2 >> 32));
      hv.w = __uint_as_float((u32)(v3 >> 32));
      ((float4*)lds_h)[tid] = hv;
      __syncthreads();  // B1
      const int c0 = lds_conv[0], c1 = lds_conv[1], c2 = lds_conv[2], c3 = lds_conv[3];
      const int convdec = ((c0 | c1 | c2 | c3) & 1) | (((c0 & c1 & c2 & c3) >> 1) & 1);

      if (convdec) {
        const int col = tid & 7;
        for (int tt = t + (tid >> 3); tt < n; tt += 32)
          __builtin_nontemporal_store(lds_h8[tt & 1][col],
                                      &hsout[(size_t)tt * HDIM + w * 8 + col]);
        if (wave == 0 && lane < 8) {
          float hlast = ((n - 1) & 1) ? hp1 : hp0;  // h(n-1)
          float clast = ((n - 1) & 1) ? cp1 : cp0;  // c(n-1)
          cstate = clast;
          u64 pub = (u64)(u32)(sbase + n) | ((u64)__float_as_uint(hlast) << 32);
          __hip_atomic_store(&a.hq[(size_t)((sbase + n) & 1) * HDIM + w * 8 + lane], pub,
                             __ATOMIC_RELAXED, __HIP_MEMORY_SCOPE_AGENT);
        }
        __syncthreads();
        fin = true;
        continue;
      }

      float acc0 = 0.f, acc1 = 0.f, acc2 = 0.f, acc3 = 0.f;
      const float4* lh4 = (const float4*)lds_h + chunk * 8;
#pragma unroll
      for (int i = 0; i < 8; ++i) {
        float4 h4 = lh4[(i + chunk) & 7];
        acc0 += wreg[0][i].x * h4.x + wreg[0][i].y * h4.y + wreg[0][i].z * h4.z + wreg[0][i].w * h4.w;
        acc1 += wreg[1][i].x * h4.x + wreg[1][i].y * h4.y + wreg[1][i].z * h4.z + wreg[1][i].w * h4.w;
        acc2 += wreg[2][i].x * h4.x + wreg[2][i].y * h4.y + wreg[2][i].z * h4.z + wreg[2][i].w * h4.w;
        acc3 += wreg[3][i].x * h4.x + wreg[3][i].y * h4.y + wreg[3][i].z * h4.z + wreg[3][i].w * h4.w;
      }
      {
        float4 p; p.x = acc0; p.y = acc1; p.z = acc2; p.w = acc3;
        *(float4*)&lds_part[chunk * 36 + rowgrp * 4] = p;
      }
      __syncthreads();  // B2

      if (wave == 0) {
        // split reduce: half lanes sum cc 0..15, other half cc 16..31, merge via xor-32;
        // pairwise tree (depth 4) instead of serial chain (depth 16)
        const int r32 = lane & 31;
        const int ccb = (lane >> 5) * 16;
        float sv[16];
#pragma unroll
        for (int cc = 0; cc < 16; ++cc) sv[cc] = lds_part[(ccb + cc) * 36 + r32];
        float sum = (((sv[0] + sv[1]) + (sv[2] + sv[3])) + ((sv[4] + sv[5]) + (sv[6] + sv[7]))) +
                    (((sv[8] + sv[9]) + (sv[10] + sv[11])) + ((sv[12] + sv[13]) + (sv[14] + sv[15])));
        sum += __shfl_xor(sum, 32);
        sum += (t == tspecial) ? my_gf : my_gc;
        // parallel nonlinearity: gate = r32>>3 (0=i,1=f,2=g(tanh),3=o)
        const bool is_t = ((r32 >> 3) == 2);
        float xx = is_t ? fminf(fmaxf(sum + sum, -30.f), 30.f) : sum;
        float e = expf(-xx);
        float num = is_t ? (1.f - e) : 1.f;
        float act = num / (1.f + e);
        const int j = lane & 7;
        float iv = __shfl(act, j);
        float fv = __shfl(act, 8 + j);
        float gv = __shfl(act, 16 + j);
        float ov = __shfl(act, 24 + j);
        if (lane < 8) {
          float cnew = fv * cstate + iv * gv;
          float hn = ov * tanhf(cnew);
          float h2 = (t & 1) ? hp1 : hp0;   // h(t-2)
          float c2v = (t & 1) ? cp1 : cp0;  // c(t-2)
          int stab = (fabsf(hn - h2) <= CONV_TOL) &&
                     (fabsf(cnew - c2v) <= CONV_TOL) &&
                     (t > tspecial + 2) && (t >= 32);
          if (t & 1) { hp1 = hn; cp1 = cnew; } else { hp0 = hn; cp0 = cnew; }
          cstate = cnew;
          // publish FIRST — single-wave coalesced 64B publish, the critical property
          u32 tagw = (u32)(s + 1) | ((u32)stab << 31);
          u64 pub = (u64)tagw | ((u64)__float_as_uint(hn) << 32);
          __hip_atomic_store(&a.hq[(size_t)((s + 1) & 1) * HDIM + w * 8 + j], pub,
                             __ATOMIC_RELAXED, __HIP_MEMORY_SCOPE_AGENT);
          lds_h8[t & 1][j] = hn;
          __builtin_nontemporal_store(hn, &hsout[(size_t)t * HDIM + w * 8 + j]);
        }
      }
    }
  }
}

// ---------------- beta via tiled GEMM; lin1_w transposed on the fly during B-staging ----------------
// Tile: 128 t x 64 j, K-panels of 32. Grid (n/128, HDIM/64). Each thread: 8t x 4j micro-tile.
// B-staging reads lin1_w[j][k] float4-along-k and transposes via scalar LDS writes
// (bank = j%32 -> 2-way aliasing = free). Bs contents bit-identical to the old L1T path;
// removes the transpose kernel + 4MB L1T round-trip.
__global__ __launch_bounds__(256) void beta_gemm_kernel(
    const float* __restrict__ hsl, const float* __restrict__ hsr,
    const float* __restrict__ l1w, const float* __restrict__ b1,
    const float* __restrict__ u, float* __restrict__ beta) {
  __shared__ float As[32][128];
  __shared__ float Bs[32][64];
  const int tid = threadIdx.x;
  const int t0 = blockIdx.x * 128;
  const int j0 = blockIdx.y * 64;
  const int tm = tid >> 4;       // 0..15 -> rows t0 + tm*8 .. +7
  const int tj = tid & 15;       // 0..15 -> cols j0 + tj*4 .. +3
  const int sr = tid >> 1;       // A-staging row 0..127
  const int sc = (tid & 1) * 4;  // A-staging float4 col base

  float acc[8][4] = {};
  const float4 uv = *(const float4*)(u + j0 + tj * 4);
  const float4 bv = *(const float4*)(b1 + j0 + tj * 4);

  const float4* l4base = (const float4*)(hsl + (size_t)(t0 + sr) * HDIM);
  const float4* r4base = (const float4*)(hsr + (size_t)(t0 + sr) * HDIM);
  const int bj = tid & 63;        // j within tile for B-staging
  const int bkq = tid >> 6;       // 0..3 -> k-quads bkq and bkq+4
  const float* wrow = l1w + (size_t)(j0 + bj) * HDIM;

  float4 ra[4], rb[4], rc0, rc1;
  {  // prologue: panel 0 into registers
#pragma unroll
    for (int i = 0; i < 4; ++i) { ra[i] = l4base[sc + i]; rb[i] = r4base[sc + i]; }
    rc0 = *(const float4*)(wrow + bkq * 4);
    rc1 = *(const float4*)(wrow + (bkq + 4) * 4);
  }

  for (int k0 = 0; k0 < HDIM; k0 += 32) {
    {  // commit registers to LDS
#pragma unroll
      for (int i = 0; i < 4; ++i) {
        As[(sc + i) * 4 + 0][sr] = ra[i].x * rb[i].x;
        As[(sc + i) * 4 + 1][sr] = ra[i].y * rb[i].y;
        As[(sc + i) * 4 + 2][sr] = ra[i].z * rb[i].z;
        As[(sc + i) * 4 + 3][sr] = ra[i].w * rb[i].w;
      }
      Bs[bkq * 4 + 0][bj] = rc0.x;
      Bs[bkq * 4 + 1][bj] = rc0.y;
      Bs[bkq * 4 + 2][bj] = rc0.z;
      Bs[bkq * 4 + 3][bj] = rc0.w;
      Bs[(bkq + 4) * 4 + 0][bj] = rc1.x;
      Bs[(bkq + 4) * 4 + 1][bj] = rc1.y;
      Bs[(bkq + 4) * 4 + 2][bj] = rc1.z;
      Bs[(bkq + 4) * 4 + 3][bj] = rc1.w;
    }
    __syncthreads();
    if (k0 + 32 < HDIM) {  // prefetch next panel; vmcnt stays outstanding over compute
      const int kn = (k0 + 32) / 4;
#pragma unroll
      for (int i = 0; i < 4; ++i) { ra[i] = l4base[kn + sc + i]; rb[i] = r4base[kn + sc + i]; }
      rc0 = *(const float4*)(wrow + k0 + 32 + bkq * 4);
      rc1 = *(const float4*)(wrow + k0 + 32 + (bkq + 4) * 4);
    }
#pragma unroll
    for (int kk = 0; kk < 32; ++kk) {
      float4 a0 = *(float4*)&As[kk][tm * 8];
      float4 a1 = *(float4*)&As[kk][tm * 8 + 4];
      float4 b = *(float4*)&Bs[kk][tj * 4];
      float ar[8] = {a0.x, a0.y, a0.z, a0.w, a1.x, a1.y, a1.z, a1.w};
      float bc[4] = {b.x, b.y, b.z, b.w};
#pragma unroll
      for (int r = 0; r < 8; ++r)
#pragma unroll
        for (int c = 0; c < 4; ++c) acc[r][c] += ar[r] * bc[c];
    }
    __syncthreads();
  }
  // epilogue: pb[r] = sum_c u[j]*tanh(acc + b1[j]); reduce over the 16 tj lanes; atomicAdd
  float ures[4] = {uv.x, uv.y, uv.z, uv.w};
  float bres[4] = {bv.x, bv.y, bv.z, bv.w};
#pragma unroll
  for (int r = 0; r < 8; ++r) {
    float pb = ures[0] * tanhf(acc[r][0] + bres[0]) + ures[1] * tanhf(acc[r][1] + bres[1]) +
               ures[2] * tanhf(acc[r][2] + bres[2]) + ures[3] * tanhf(acc[r][3] + bres[3]);
#pragma unroll
    for (int off = 1; off < 16; off <<= 1) pb += __shfl_xor(pb, off);
    if (tj == 0) atomicAdd(&beta[t0 + tm * 8 + r], pb);
  }
}

// ---------------- svec with fused softmax: s[h] += sum_t softmax(beta)[t]*O[t][h] ----------------
__global__ __launch_bounds__(256) void svec_kernel(const float* __restrict__ beta,
                                                   const float* __restrict__ hsl,
                                                   const float* __restrict__ hsr,
                                                   float* __restrict__ svec, int n) {
  __shared__ float sm[8];
  __shared__ float wts[256];
  __shared__ float red[4][64];
  const int tid = threadIdx.x, lane = tid & 63, wv = tid >> 6;
  // softmax stats over the full beta (small; L2-broadcast across blocks)
  float m = -3.4e38f;
  for (int i = tid; i < n; i += 256) m = fmaxf(m, beta[i]);
  for (int off = 32; off; off >>= 1) m = fmaxf(m, __shfl_xor(m, off));
  if (lane == 0) sm[wv] = m;
  __syncthreads();
  const float M = fmaxf(fmaxf(sm[0], sm[1]), fmaxf(sm[2], sm[3]));
  float z = 0.f;
  for (int i = tid; i < n; i += 256) z += expf(beta[i] - M);
  for (int off = 32; off; off >>= 1) z += __shfl_xor(z, off);
  if (lane == 0) sm[4 + wv] = z;
  __syncthreads();
  const float invZ = 1.f / (sm[4] + sm[5] + sm[6] + sm[7]);
  const int tlen = n / gridDim.y;   // 256 for n=2048, gridDim.y=8
  const int tbeg = blockIdx.y * tlen;
  for (int i = tid; i < tlen; i += 256) wts[i] = expf(beta[tbeg + i] - M) * invZ;
  __syncthreads();
  const int h = blockIdx.x * 64 + lane;
  const int ts = wv;
  float s = 0.f;
  for (int t = ts; t < tlen; t += 4)
    s += wts[t] * hsl[(size_t)(tbeg + t) * HDIM + h] * hsr[(size_t)(tbeg + t) * HDIM + h];
  red[ts][lane] = s;
  __syncthreads();
  if (tid < 64) {
    float tot = red[0][tid] + red[1][tid] + red[2][tid] + red[3][tid];
    atomicAdd(&svec[blockIdx.x * 64 + tid], tot);
  }
}

// ---------------- out[r] = lin2_w[r] . s + lin2_b[r] ----------------
__global__ void final_kernel(const float* __restrict__ svec, const float* __restrict__ l2w,
                             const float* __restrict__ l2b, float* __restrict__ out) {
  int r = threadIdx.x >> 6, lane = threadIdx.x & 63;
  float s = 0.f;
  for (int k = lane; k < HDIM; k += 64) s += l2w[(size_t)r * HDIM + k] * svec[k];
  for (int off = 32; off; off >>= 1) s += __shfl_xor(s, off);
  if (lane == 0) out[r] = s + l2b[r];
}

extern "C" void kernel_launch(void* const* d_in, const int* in_sizes, int n_in,
                              void* d_out, int out_size, void* d_ws, size_t ws_size,
                              hipStream_t stream) {
  const int* x = (const int*)d_in[0];
  const int* tstart = (const int*)d_in[1];
  const int* tend = (const int*)d_in[2];
  const float* emb = (const float*)d_in[3];
  const float* wih_l = (const float*)d_in[4];
  const float* whh_l = (const float*)d_in[5];
  const float* bih_l = (const float*)d_in[6];
  const float* bhh_l = (const float*)d_in[7];
  const float* wih_r = (const float*)d_in[8];
  const float* whh_r = (const float*)d_in[9];
  const float* bih_r = (const float*)d_in[10];
  const float* bhh_r = (const float*)d_in[11];
  const float* l1w = (const float*)d_in[12];
  const float* l1b = (const float*)d_in[13];
  const float* u = (const float*)d_in[14];
  const float* l2w = (const float*)d_in[15];
  const float* l2b = (const float*)d_in[16];
  const int n = in_sizes[0];  // 2048
  (void)n_in; (void)out_size; (void)ws_size;

  float* ws = (float*)d_ws;
  float* target = ws;                     // 1024
  float* seqfl = ws + 1024;               // 1024
  float* seqfr = ws + 2048;               // 1024
  float* glc = ws + 3072;                 // 4096
  float* glf = glc + 4096;                // 4096
  float* grc = glf + 4096;                // 4096
  float* grf = grc + 4096;                // 4096
  u64* hq = (u64*)(grf + 4096);           // 2*1024 u64 (8B aligned)
  float* hsl = (float*)(hq + 2 * HDIM);   // n*1024
  float* hsr = hsl + (size_t)n * HDIM;    // n*1024
  float* beta = hsr + (size_t)n * HDIM;   // n  (L1T buffer removed)
  float* svec = beta + n;                 // 1024

  setup_kernel<<<1, 1024, 0, stream>>>(x, tstart, tend, emb, target, seqfl, seqfr, hq,
                                       beta, svec, n);
  gateconst_kernel<<<dim3(1024, 2), 256, 0, stream>>>(wih_l, bih_l, bhh_l, wih_r, bih_r, bhh_r,
                                                      target, seqfl, seqfr, glc, glf, grc, grf);
  RecArgs ra;
  ra.whh_l = whh_l; ra.whh_r = whh_r;
  ra.glc = glc; ra.glf = glf; ra.grc = grc; ra.grf = grf;
  ra.hq = hq; ra.hsl = hsl; ra.hsr = hsr;
  ra.pstart = tstart; ra.pend = tend; ra.n = n;
  // Plain launch (kept: non-rec 451->416us vs cooperative). Co-residency trivially
  // guaranteed: 128 WGs x 4 waves = 512 waves << 8192 device capacity.
  rec_kernel<<<dim3(NWG), dim3(TPB), 0, stream>>>(ra);

  beta_gemm_kernel<<<dim3(n / 128, HDIM / 64), 256, 0, stream>>>(hsl, hsr, l1w, l1b, u, beta);
  svec_kernel<<<dim3(16, 8), 256, 0, stream>>>(beta, hsl, hsr, svec, n);
  final_kernel<<<1, 192, 0, stream>>>(svec, l2w, l2b, (float*)d_out);
}

// Round 11
// 803.295 us; speedup vs baseline: 1.5232x; 1.0152x over previous
//
#include <hip/hip_runtime.h>
#include <math.h>

#define HDIM 1024
#define NWG 128
#define TPB 512
#define CONV_TOL 1.0e-5f

typedef unsigned long long u64;
typedef unsigned int u32;

struct RecArgs {
  const float* whh_l; const float* whh_r;
  const float* glc; const float* glf; const float* grc; const float* grf;
  u64* hq;            // [2][HDIM] tagged slots: low32 = tag | stable<<31, high32 = f32 bits
  float* hsl;         // [n][HDIM]
  float* hsr;         // [n][HDIM]
  const int* pstart; const int* pend;
  int n;
};

// ---------------- setup: target vector, special rows, tagged-state init, accum zeroing ----------------
__global__ void setup_kernel(const int* __restrict__ x, const int* ts, const int* te,
                             const float* __restrict__ emb,
                             float* target, float* seqfl, float* seqfr,
                             u64* hq, float* beta, float* svec, int n) {
  int e = threadIdx.x;  // 0..1023
  int start = ts[0], end = te[0];
  int first_l = (start > 0) ? 0 : (end + 1);
  int first_r = (end < n - 1) ? (n - 1) : (start - 1);
  int fl = min(max(first_l, 0), n - 1);
  int fr = min(max(first_r, 0), n - 1);
  float sum = 0.f;
  for (int p = start; p <= end; ++p) sum += emb[(size_t)x[p] * HDIM + e];
  target[e] = sum / (float)(end - start + 1);
  seqfl[e] = emb[(size_t)x[fl] * HDIM + e];
  seqfr[e] = emb[(size_t)x[fr] * HDIM + e];
  // tag=0 (h input for step 0), value = 0.0f, stable=0 — both parities
  hq[e] = 0ull;
  hq[HDIM + e] = 0ull;
  for (int i = e; i < n; i += 1024) beta[i] = 0.f;
  svec[e] = 0.f;
}

// ---------------- gate-constant vectors: w_ih@v + b_ih + b_hh ----------------
__global__ __launch_bounds__(256) void gateconst_kernel(
    const float* __restrict__ wih_l, const float* bih_l, const float* bhh_l,
    const float* __restrict__ wih_r, const float* bih_r, const float* bhh_r,
    const float* __restrict__ target, const float* __restrict__ seqfl,
    const float* __restrict__ seqfr,
    float* glc, float* glf, float* grc, float* grf) {
  int side = blockIdx.y;
  const float* wih = side ? wih_r : wih_l;
  const float* bih = side ? bih_r : bih_l;
  const float* bhh = side ? bhh_r : bhh_l;
  const float* sf = side ? seqfr : seqfl;
  float* outc = side ? grc : glc;
  float* outf = side ? grf : glf;
  int wv = threadIdx.x >> 6, lane = threadIdx.x & 63;
  int r = blockIdx.x * 4 + wv;  // 0..4095
  const float4* wrow = (const float4*)(wih + (size_t)r * HDIM);
  const float4* tg4 = (const float4*)target;
  const float4* sf4 = (const float4*)sf;
  float dc = 0.f, df = 0.f;
#pragma unroll
  for (int k = 0; k < 4; ++k) {
    float4 w4 = wrow[lane + 64 * k];
    float4 t4 = tg4[lane + 64 * k];
    float4 s4 = sf4[lane + 64 * k];
    dc += w4.x * t4.x + w4.y * t4.y + w4.z * t4.z + w4.w * t4.w;
    df += w4.x * s4.x + w4.y * s4.y + w4.z * s4.z + w4.w * s4.w;
  }
  for (int off = 32; off; off >>= 1) {
    dc += __shfl_xor(dc, off);
    df += __shfl_xor(df, off);
  }
  if (lane == 0) {
    float bb = bih[r] + bhh[r];
    outc[r] = dc + bb;
    outf[r] = df + bb;
  }
}

// ---------------- persistent recurrence ----------------
// R6 structure (poll by threads 0-255, lds_part staging, wave0-only epilogue,
// SINGLE-WAVE coalesced lanes<8 publish — the critical property) with R9 delta:
// TPB 256->512: matvec split to 2 rows/thread (64 MACs), 2 waves/SIMD for LDS-latency
// hiding. This isolates the half of Round-1's change that was NOT the publish
// (R1 = TPB512 + distributed publish regressed; R6 showed publish is critical;
// this tests whether the 512-thread matvec split alone helps or hurts).
// Arithmetic bit-identical to R6 (same per-row chunk order, same epilogue).
__global__ __launch_bounds__(TPB, 1) void rec_kernel(RecArgs a) {
  const int w = blockIdx.x;
  const int tid = threadIdx.x;
  const int wave = tid >> 6;     // 0..7
  const int lane = tid & 63;
  const int chunk = tid & 31;    // 32-col chunk of the k dimension
  const int rowgrp = tid >> 5;   // 0..15 -> local rows rowgrp*2, rowgrp*2+1
  const int n = a.n;

  __shared__ float lds_h[HDIM];
  __shared__ float lds_part[32 * 36];  // [chunk][row] pitch 36 floats
  __shared__ float lds_h8[2][8];       // [local parity][unit]
  __shared__ int lds_conv[4];

  const int start = a.pstart[0];
  const int end = a.pend[0];
  const int first_l = (start > 0) ? 0 : (end + 1);
  const int first_r = (end < n - 1) ? (n - 1) : (start - 1);

  float4 wreg[2][8];  // constant-indexed only => guaranteed VGPR residency
  float cstate = 0.f;
  float hp0 = 0.f, hp1 = 0.f, cp0 = 0.f, cp1 = 0.f;  // parity history (wave0 lanes<8)

  for (int pass = 0; pass < 2; ++pass) {
    const float* whh = pass ? a.whh_r : a.whh_l;
    const float* gcv = pass ? a.grc : a.glc;
    const float* gfv = pass ? a.grf : a.glf;
    float* hsout = pass ? a.hsr : a.hsl;
    const int tspecial = pass ? (n - 1 - first_r) : first_l;
    const int sbase = pass * n;

#pragma unroll
    for (int r = 0; r < 2; ++r) {
      const int lr = rowgrp * 2 + r;
      const int grow = (lr >> 3) * HDIM + w * 8 + (lr & 7);
      const float4* wr = (const float4*)(whh + (size_t)grow * HDIM) + chunk * 8;
#pragma unroll
      for (int i = 0; i < 8; ++i) wreg[r][i] = wr[(i + chunk) & 7];
    }
    // gate constants for wave0's gate-row mapping: r32 = lane&31 -> gate r32>>3, unit r32&7.
    float my_gc = 0.f, my_gf = 0.f;
    if (wave == 0) {
      const int r32 = lane & 31;
      const int R = (r32 >> 3) * HDIM + w * 8 + (r32 & 7);
      my_gc = gcv[R];
      my_gf = gfv[R];
    }

    bool fin = false;
    for (int t = 0; t < n && !fin; ++t) {
      const int s = sbase + t;
      if (tid < 256) {  // waves 0-3 poll (same layout as R6)
        const u64* slot = a.hq + (size_t)(s & 1) * HDIM + tid * 4;
        u64 v0 = 0, v1 = 0, v2 = 0, v3 = 0;
        u32 t0 = 0, t1 = 0, t2 = 0, t3 = 0;
        int done = 0;
        int guard = 0;
        for (;;) {
          if (!done) {
            v0 = __hip_atomic_load(slot + 0, __ATOMIC_RELAXED, __HIP_MEMORY_SCOPE_AGENT);
            v1 = __hip_atomic_load(slot + 1, __ATOMIC_RELAXED, __HIP_MEMORY_SCOPE_AGENT);
            v2 = __hip_atomic_load(slot + 2, __ATOMIC_RELAXED, __HIP_MEMORY_SCOPE_AGENT);
            v3 = __hip_atomic_load(slot + 3, __ATOMIC_RELAXED, __HIP_MEMORY_SCOPE_AGENT);
            t0 = (u32)v0 & 0x7fffffffu; t1 = (u32)v1 & 0x7fffffffu;
            t2 = (u32)v2 & 0x7fffffffu; t3 = (u32)v3 & 0x7fffffffu;
            done = (t0 >= (u32)s) && (t1 >= (u32)s) && (t2 >= (u32)s) && (t3 >= (u32)s);
          }
          if (__all(done)) break;
          if (++guard > 4000000) break;  // anti-hang safety
        }
        int anyg = (t0 > (u32)s) || (t1 > (u32)s) || (t2 > (u32)s) || (t3 > (u32)s);
        int stall = (int)((((u32)v0) >> 31) & (((u32)v1) >> 31) &
                          (((u32)v2) >> 31) & (((u32)v3) >> 31));
        int wany = __any(anyg);
        int wall = __all(stall);
        if (lane == 0) lds_conv[wave] = (wall << 1) | wany;
        float4 hv;
        hv.x = __uint_as_float((u32)(v0 >> 32));
        hv.y = __uint_as_float((u32)(v1 >> 32));
        hv.z = __uint_as_float((u32)(v2 >> 32));
        hv.w = __uint_as_float((u32)(v3 >> 32));
        ((float4*)lds_h)[tid] = hv;
      }
      __syncthreads();  // B1
      const int c0 = lds_conv[0], c1 = lds_conv[1], c2 = lds_conv[2], c3 = lds_conv[3];
      const int convdec = ((c0 | c1 | c2 | c3) & 1) | (((c0 & c1 & c2 & c3) >> 1) & 1);

      if (convdec) {
        const int col = tid & 7;
        for (int tt = t + (tid >> 3); tt < n; tt += 64)
          __builtin_nontemporal_store(lds_h8[tt & 1][col],
                                      &hsout[(size_t)tt * HDIM + w * 8 + col]);
        if (wave == 0 && lane < 8) {
          float hlast = ((n - 1) & 1) ? hp1 : hp0;  // h(n-1)
          float clast = ((n - 1) & 1) ? cp1 : cp0;  // c(n-1)
          cstate = clast;
          u64 pub = (u64)(u32)(sbase + n) | ((u64)__float_as_uint(hlast) << 32);
          __hip_atomic_store(&a.hq[(size_t)((sbase + n) & 1) * HDIM + w * 8 + lane], pub,
                             __ATOMIC_RELAXED, __HIP_MEMORY_SCOPE_AGENT);
        }
        __syncthreads();
        fin = true;
        continue;
      }

      float acc0 = 0.f, acc1 = 0.f;
      const float4* lh4 = (const float4*)lds_h + chunk * 8;
#pragma unroll
      for (int i = 0; i < 8; ++i) {
        float4 h4 = lh4[(i + chunk) & 7];
        acc0 += wreg[0][i].x * h4.x + wreg[0][i].y * h4.y + wreg[0][i].z * h4.z + wreg[0][i].w * h4.w;
        acc1 += wreg[1][i].x * h4.x + wreg[1][i].y * h4.y + wreg[1][i].z * h4.z + wreg[1][i].w * h4.w;
      }
      {
        float2 p; p.x = acc0; p.y = acc1;
        *(float2*)&lds_part[chunk * 36 + rowgrp * 2] = p;  // rows rowgrp*2, +1
      }
      __syncthreads();  // B2

      if (wave == 0) {  // identical to R6 epilogue (bit-identical arithmetic)
        const int r32 = lane & 31;
        const int ccb = (lane >> 5) * 16;
        float sv[16];
#pragma unroll
        for (int cc = 0; cc < 16; ++cc) sv[cc] = lds_part[(ccb + cc) * 36 + r32];
        float sum = (((sv[0] + sv[1]) + (sv[2] + sv[3])) + ((sv[4] + sv[5]) + (sv[6] + sv[7]))) +
                    (((sv[8] + sv[9]) + (sv[10] + sv[11])) + ((sv[12] + sv[13]) + (sv[14] + sv[15])));
        sum += __shfl_xor(sum, 32);
        sum += (t == tspecial) ? my_gf : my_gc;
        const bool is_t = ((r32 >> 3) == 2);
        float xx = is_t ? fminf(fmaxf(sum + sum, -30.f), 30.f) : sum;
        float e = expf(-xx);
        float num = is_t ? (1.f - e) : 1.f;
        float act = num / (1.f + e);
        const int j = lane & 7;
        float iv = __shfl(act, j);
        float fv = __shfl(act, 8 + j);
        float gv = __shfl(act, 16 + j);
        float ov = __shfl(act, 24 + j);
        if (lane < 8) {
          float cnew = fv * cstate + iv * gv;
          float hn = ov * tanhf(cnew);
          float h2 = (t & 1) ? hp1 : hp0;   // h(t-2)
          float c2v = (t & 1) ? cp1 : cp0;  // c(t-2)
          int stab = (fabsf(hn - h2) <= CONV_TOL) &&
                     (fabsf(cnew - c2v) <= CONV_TOL) &&
                     (t > tspecial + 2) && (t >= 32);
          if (t & 1) { hp1 = hn; cp1 = cnew; } else { hp0 = hn; cp0 = cnew; }
          cstate = cnew;
          // publish FIRST — single-wave coalesced 64B publish, the critical property
          u32 tagw = (u32)(s + 1) | ((u32)stab << 31);
          u64 pub = (u64)tagw | ((u64)__float_as_uint(hn) << 32);
          __hip_atomic_store(&a.hq[(size_t)((s + 1) & 1) * HDIM + w * 8 + j], pub,
                             __ATOMIC_RELAXED, __HIP_MEMORY_SCOPE_AGENT);
          lds_h8[t & 1][j] = hn;
          __builtin_nontemporal_store(hn, &hsout[(size_t)t * HDIM + w * 8 + j]);
        }
      }
    }
  }
}

// ---------------- beta via tiled GEMM; lin1_w transposed on the fly during B-staging ----------------
// R9: 64t x 64j tiles, grid (n/64, HDIM/64) = 512 blocks -> 2 blocks/CU (was 1) for
// latency hiding. Per-thread micro-tile 4t x 4j. Same k-order per (t,j) -> beta
// bit-identical to the 128x64 version.
__global__ __launch_bounds__(256) void beta_gemm_kernel(
    const float* __restrict__ hsl, const float* __restrict__ hsr,
    const float* __restrict__ l1w, const float* __restrict__ b1,
    const float* __restrict__ u, float* __restrict__ beta) {
  __shared__ float As[32][64];
  __shared__ float Bs[32][64];
  const int tid = threadIdx.x;
  const int t0 = blockIdx.x * 64;
  const int j0 = blockIdx.y * 64;
  const int tm = tid >> 4;       // 0..15 -> rows t0 + tm*4 .. +3
  const int tj = tid & 15;       // 0..15 -> cols j0 + tj*4 .. +3
  const int sr = tid >> 2;       // A-staging row 0..63
  const int sc = (tid & 3) * 2;  // A-staging float4 indices sc, sc+1

  float acc[4][4] = {};
  const float4 uv = *(const float4*)(u + j0 + tj * 4);
  const float4 bv = *(const float4*)(b1 + j0 + tj * 4);

  const float4* l4base = (const float4*)(hsl + (size_t)(t0 + sr) * HDIM);
  const float4* r4base = (const float4*)(hsr + (size_t)(t0 + sr) * HDIM);
  const int bj = tid & 63;        // j within tile for B-staging
  const int bkq = tid >> 6;       // 0..3 -> k-quads bkq and bkq+4
  const float* wrow = l1w + (size_t)(j0 + bj) * HDIM;

  float4 ra[2], rb[2], rc0, rc1;
  {  // prologue: panel 0 into registers
#pragma unroll
    for (int i = 0; i < 2; ++i) { ra[i] = l4base[sc + i]; rb[i] = r4base[sc + i]; }
    rc0 = *(const float4*)(wrow + bkq * 4);
    rc1 = *(const float4*)(wrow + (bkq + 4) * 4);
  }

  for (int k0 = 0; k0 < HDIM; k0 += 32) {
    {  // commit registers to LDS
#pragma unroll
      for (int i = 0; i < 2; ++i) {
        As[(sc + i) * 4 + 0][sr] = ra[i].x * rb[i].x;
        As[(sc + i) * 4 + 1][sr] = ra[i].y * rb[i].y;
        As[(sc + i) * 4 + 2][sr] = ra[i].z * rb[i].z;
        As[(sc + i) * 4 + 3][sr] = ra[i].w * rb[i].w;
      }
      Bs[bkq * 4 + 0][bj] = rc0.x;
      Bs[bkq * 4 + 1][bj] = rc0.y;
      Bs[bkq * 4 + 2][bj] = rc0.z;
      Bs[bkq * 4 + 3][bj] = rc0.w;
      Bs[(bkq + 4) * 4 + 0][bj] = rc1.x;
      Bs[(bkq + 4) * 4 + 1][bj] = rc1.y;
      Bs[(bkq + 4) * 4 + 2][bj] = rc1.z;
      Bs[(bkq + 4) * 4 + 3][bj] = rc1.w;
    }
    __syncthreads();
    if (k0 + 32 < HDIM) {  // prefetch next panel; vmcnt stays outstanding over compute
      const int kn = (k0 + 32) / 4;
#pragma unroll
      for (int i = 0; i < 2; ++i) { ra[i] = l4base[kn + sc + i]; rb[i] = r4base[kn + sc + i]; }
      rc0 = *(const float4*)(wrow + k0 + 32 + bkq * 4);
      rc1 = *(const float4*)(wrow + k0 + 32 + (bkq + 4) * 4);
    }
#pragma unroll
    for (int kk = 0; kk < 32; ++kk) {
      float4 a = *(float4*)&As[kk][tm * 4];
      float4 b = *(float4*)&Bs[kk][tj * 4];
      float ar[4] = {a.x, a.y, a.z, a.w};
      float bc[4] = {b.x, b.y, b.z, b.w};
#pragma unroll
      for (int r = 0; r < 4; ++r)
#pragma unroll
        for (int c = 0; c < 4; ++c) acc[r][c] += ar[r] * bc[c];
    }
    __syncthreads();
  }
  // epilogue: pb[r] = sum_c u[j]*tanh(acc + b1[j]); reduce over the 16 tj lanes; atomicAdd
  float ures[4] = {uv.x, uv.y, uv.z, uv.w};
  float bres[4] = {bv.x, bv.y, bv.z, bv.w};
#pragma unroll
  for (int r = 0; r < 4; ++r) {
    float pb = ures[0] * tanhf(acc[r][0] + bres[0]) + ures[1] * tanhf(acc[r][1] + bres[1]) +
               ures[2] * tanhf(acc[r][2] + bres[2]) + ures[3] * tanhf(acc[r][3] + bres[3]);
#pragma unroll
    for (int off = 1; off < 16; off <<= 1) pb += __shfl_xor(pb, off);
    if (tj == 0) atomicAdd(&beta[t0 + tm * 4 + r], pb);
  }
}

// ---------------- svec with fused softmax: s[h] += sum_t softmax(beta)[t]*O[t][h] ----------------
__global__ __launch_bounds__(256) void svec_kernel(const float* __restrict__ beta,
                                                   const float* __restrict__ hsl,
                                                   const float* __restrict__ hsr,
                                                   float* __restrict__ svec, int n) {
  __shared__ float sm[8];
  __shared__ float wts[256];
  __shared__ float red[4][64];
  const int tid = threadIdx.x, lane = tid & 63, wv = tid >> 6;
  // softmax stats over the full beta (small; L2-broadcast across blocks)
  float m = -3.4e38f;
  for (int i = tid; i < n; i += 256) m = fmaxf(m, beta[i]);
  for (int off = 32; off; off >>= 1) m = fmaxf(m, __shfl_xor(m, off));
  if (lane == 0) sm[wv] = m;
  __syncthreads();
  const float M = fmaxf(fmaxf(sm[0], sm[1]), fmaxf(sm[2], sm[3]));
  float z = 0.f;
  for (int i = tid; i < n; i += 256) z += expf(beta[i] - M);
  for (int off = 32; off; off >>= 1) z += __shfl_xor(z, off);
  if (lane == 0) sm[4 + wv] = z;
  __syncthreads();
  const float invZ = 1.f / (sm[4] + sm[5] + sm[6] + sm[7]);
  const int tlen = n / gridDim.y;   // 256 for n=2048, gridDim.y=8
  const int tbeg = blockIdx.y * tlen;
  for (int i = tid; i < tlen; i += 256) wts[i] = expf(beta[tbeg + i] - M) * invZ;
  __syncthreads();
  const int h = blockIdx.x * 64 + lane;
  const int ts = wv;
  float s = 0.f;
  for (int t = ts; t < tlen; t += 4)
    s += wts[t] * hsl[(size_t)(tbeg + t) * HDIM + h] * hsr[(size_t)(tbeg + t) * HDIM + h];
  red[ts][lane] = s;
  __syncthreads();
  if (tid < 64) {
    float tot = red[0][tid] + red[1][tid] + red[2][tid] + red[3][tid];
    atomicAdd(&svec[blockIdx.x * 64 + tid], tot);
  }
}

// ---------------- out[r] = lin2_w[r] . s + lin2_b[r] ----------------
__global__ void final_kernel(const float* __restrict__ svec, const float* __restrict__ l2w,
                             const float* __restrict__ l2b, float* __restrict__ out) {
  int r = threadIdx.x >> 6, lane = threadIdx.x & 63;
  float s = 0.f;
  for (int k = lane; k < HDIM; k += 64) s += l2w[(size_t)r * HDIM + k] * svec[k];
  for (int off = 32; off; off >>= 1) s += __shfl_xor(s, off);
  if (lane == 0) out[r] = s + l2b[r];
}

extern "C" void kernel_launch(void* const* d_in, const int* in_sizes, int n_in,
                              void* d_out, int out_size, void* d_ws, size_t ws_size,
                              hipStream_t stream) {
  const int* x = (const int*)d_in[0];
  const int* tstart = (const int*)d_in[1];
  const int* tend = (const int*)d_in[2];
  const float* emb = (const float*)d_in[3];
  const float* wih_l = (const float*)d_in[4];
  const float* whh_l = (const float*)d_in[5];
  const float* bih_l = (const float*)d_in[6];
  const float* bhh_l = (const float*)d_in[7];
  const float* wih_r = (const float*)d_in[8];
  const float* whh_r = (const float*)d_in[9];
  const float* bih_r = (const float*)d_in[10];
  const float* bhh_r = (const float*)d_in[11];
  const float* l1w = (const float*)d_in[12];
  const float* l1b = (const float*)d_in[13];
  const float* u = (const float*)d_in[14];
  const float* l2w = (const float*)d_in[15];
  const float* l2b = (const float*)d_in[16];
  const int n = in_sizes[0];  // 2048
  (void)n_in; (void)out_size; (void)ws_size;

  float* ws = (float*)d_ws;
  float* target = ws;                     // 1024
  float* seqfl = ws + 1024;               // 1024
  float* seqfr = ws + 2048;               // 1024
  float* glc = ws + 3072;                 // 4096
  float* glf = glc + 4096;                // 4096
  float* grc = glf + 4096;                // 4096
  float* grf = grc + 4096;                // 4096
  u64* hq = (u64*)(grf + 4096);           // 2*1024 u64 (8B aligned)
  float* hsl = (float*)(hq + 2 * HDIM);   // n*1024
  float* hsr = hsl + (size_t)n * HDIM;    // n*1024
  float* beta = hsr + (size_t)n * HDIM;   // n
  float* svec = beta + n;                 // 1024

  setup_kernel<<<1, 1024, 0, stream>>>(x, tstart, tend, emb, target, seqfl, seqfr, hq,
                                       beta, svec, n);
  gateconst_kernel<<<dim3(1024, 2), 256, 0, stream>>>(wih_l, bih_l, bhh_l, wih_r, bih_r, bhh_r,
                                                      target, seqfl, seqfr, glc, glf, grc, grf);
  RecArgs ra;
  ra.whh_l = whh_l; ra.whh_r = whh_r;
  ra.glc = glc; ra.glf = glf; ra.grc = grc; ra.grf = grf;
  ra.hq = hq; ra.hsl = hsl; ra.hsr = hsr;
  ra.pstart = tstart; ra.pend = tend; ra.n = n;
  // Plain launch. Co-residency trivially guaranteed: 128 WGs x 8 waves = 1024 waves
  // << 8192 device capacity.
  rec_kernel<<<dim3(NWG), dim3(TPB), 0, stream>>>(ra);

  beta_gemm_kernel<<<dim3(n / 64, HDIM / 64), 256, 0, stream>>>(hsl, hsr, l1w, l1b, u, beta);
  svec_kernel<<<dim3(16, 8), 256, 0, stream>>>(beta, hsl, hsr, svec, n);
  final_kernel<<<1, 192, 0, stream>>>(svec, l2w, l2b, (float*)d_out);
}